// Round 4
// baseline (119.986 us; speedup 1.0000x reference)
//
#include <hip/hip_runtime.h>

// Adaptive Wing loss, reduction='sum', fp32 in/out.
// THETA=0.5, ALPHA=2.1, OMEGA=14.0, EPS=1.0
//   p   = 2.1 - target                      in (1.1, 2.1]
//   t   = (0.5)^p = 2^(-p)
//   A   = 28 * p * t / (1+t)
//   C   = 0.5*A - 14*ln(1+t)
//   diff = |target - input|
//   loss = diff < 0.5 ? 14*ln(1 + diff^p) : A*diff - C
//
// R2: libm -> native v_exp/v_log/v_rcp (VALUBusy 62->30%).
// R3: VGPR=16 showed 1 iter in flight -> latency-exposed (HBM 22%, VALU 30%).
//     4-deep manual unroll, 8 hoisted float4 loads per thread-iter for MLP.

#define LN2_X14 9.704060527839234f  // 14 * ln(2)

__device__ __forceinline__ float awl_elem(float x, float tg) {
    float p = 2.1f - tg;
    float t = __builtin_amdgcn_exp2f(-p);                 // 2^(-p)
    float A = 28.0f * p * t * __builtin_amdgcn_rcpf(1.0f + t);
    float l1pt = LN2_X14 * __builtin_amdgcn_logf(1.0f + t);  // 14*ln(1+t) (v_log = log2)
    float diff = fabsf(tg - x);
    float lin = fmaf(A, diff - 0.5f, l1pt);               // A*diff - C
    // diff^p = 2^(p*log2(diff)); diff==0 -> -inf -> 0 -> log2(1)=0. OK.
    float q = __builtin_amdgcn_exp2f(p * __builtin_amdgcn_logf(diff));
    float nl = LN2_X14 * __builtin_amdgcn_logf(1.0f + q);
    return diff < 0.5f ? nl : lin;
}

__device__ __forceinline__ float awl_quad(float4 a, float4 b) {
    return (awl_elem(a.x, b.x) + awl_elem(a.y, b.y))
         + (awl_elem(a.z, b.z) + awl_elem(a.w, b.w));
}

__global__ __launch_bounds__(256) void awl_partial(
    const float4* __restrict__ x, const float4* __restrict__ tg,
    float* __restrict__ part, int n4)
{
    int tid = blockIdx.x * blockDim.x + threadIdx.x;
    int stride = gridDim.x * blockDim.x;
    float acc = 0.0f;
    int i = tid;
    // 4-deep unrolled main loop: hoist all 8 loads for memory-level parallelism.
    for (; i + 3 * stride < n4; i += 4 * stride) {
        float4 a0 = x[i];
        float4 a1 = x[i + stride];
        float4 a2 = x[i + 2 * stride];
        float4 a3 = x[i + 3 * stride];
        float4 b0 = tg[i];
        float4 b1 = tg[i + stride];
        float4 b2 = tg[i + 2 * stride];
        float4 b3 = tg[i + 3 * stride];
        acc += awl_quad(a0, b0);
        acc += awl_quad(a1, b1);
        acc += awl_quad(a2, b2);
        acc += awl_quad(a3, b3);
    }
    for (; i < n4; i += stride)
        acc += awl_quad(x[i], tg[i]);

    // wave-64 reduce
    #pragma unroll
    for (int off = 32; off > 0; off >>= 1)
        acc += __shfl_down(acc, off, 64);
    __shared__ float ws[4];
    int lane = threadIdx.x & 63;
    int wid  = threadIdx.x >> 6;
    if (lane == 0) ws[wid] = acc;
    __syncthreads();
    if (threadIdx.x == 0)
        part[blockIdx.x] = (ws[0] + ws[1]) + (ws[2] + ws[3]);
}

__global__ __launch_bounds__(256) void awl_final(
    const float* __restrict__ part, int n, float* __restrict__ out)
{
    float acc = 0.0f;
    for (int i = threadIdx.x; i < n; i += 256) acc += part[i];
    #pragma unroll
    for (int off = 32; off > 0; off >>= 1)
        acc += __shfl_down(acc, off, 64);
    __shared__ float ws[4];
    int lane = threadIdx.x & 63;
    int wid  = threadIdx.x >> 6;
    if (lane == 0) ws[wid] = acc;
    __syncthreads();
    if (threadIdx.x == 0)
        out[0] = (ws[0] + ws[1]) + (ws[2] + ws[3]);
}

extern "C" void kernel_launch(void* const* d_in, const int* in_sizes, int n_in,
                              void* d_out, int out_size, void* d_ws, size_t ws_size,
                              hipStream_t stream) {
    const float* x  = (const float*)d_in[0];
    const float* tg = (const float*)d_in[1];
    float* out  = (float*)d_out;
    float* part = (float*)d_ws;

    long long n = (long long)in_sizes[0];   // 67,108,864 (divisible by 4)
    int n4 = (int)(n / 4);

    int nblk = 2048;                         // 8 blocks/CU co-resident
    int cap = (int)(ws_size / sizeof(float));
    if (cap > 0 && nblk > cap) nblk = cap;
    if (nblk < 1) nblk = 1;

    awl_partial<<<nblk, 256, 0, stream>>>((const float4*)x, (const float4*)tg, part, n4);
    awl_final<<<1, 256, 0, stream>>>(part, nblk, out);
}

// Round 5
// 97.437 us; speedup vs baseline: 1.2314x; 1.2314x over previous
//
#include <hip/hip_runtime.h>

// Adaptive Wing loss, reduction='sum', fp32 in/out.
// THETA=0.5, ALPHA=2.1, OMEGA=14.0, EPS=1.0
//   p = 2.1 - target; t = 2^(-p); A = 28*p*t/(1+t)
//   lin = A*(diff-0.5) + 14*ln(1+t);  nl = 14*ln(1+diff^p)
//   loss = diff < 0.5 ? nl : lin
// Shared-log form: z = diff<0.5 ? diff^p : t;  loss = 14*ln(1+z) + (diff<0.5 ? 0 : A*(diff-0.5))
//
// R2: libm -> native v_exp/v_log/v_rcp (VALUBusy 62->30%).
// R4: 4-deep strided unroll scattered the wave's in-flight set (8MB apart):
//     occupancy 78->58, dur 101->120. Reverted.
// R5: depth-2 CONTIGUOUS unroll (wave covers 2KB/array/iter, pair offset = 64
//     float4s), 4 loads hoisted; plus one-log select (5 trans/elem, was 6).

#define LN2_X14 9.704060527839234f  // 14 * ln(2)

__device__ __forceinline__ float awl_elem(float x, float tg) {
    float p = 2.1f - tg;
    float t = __builtin_amdgcn_exp2f(-p);                 // 2^(-p)
    float A = 28.0f * p * t * __builtin_amdgcn_rcpf(1.0f + t);
    float diff = fabsf(tg - x);
    // diff^p = 2^(p*log2(diff)); diff==0 -> -inf -> exp2 = 0. OK.
    float q = __builtin_amdgcn_exp2f(p * __builtin_amdgcn_logf(diff));
    bool lt = diff < 0.5f;
    float z = lt ? q : t;
    float extra = lt ? 0.0f : A * (diff - 0.5f);
    return fmaf(LN2_X14, __builtin_amdgcn_logf(1.0f + z), extra);
}

__device__ __forceinline__ float awl_quad(float4 a, float4 b) {
    return (awl_elem(a.x, b.x) + awl_elem(a.y, b.y))
         + (awl_elem(a.z, b.z) + awl_elem(a.w, b.w));
}

__global__ __launch_bounds__(256) void awl_partial(
    const float4* __restrict__ x, const float4* __restrict__ tg,
    float* __restrict__ part, int n4)
{
    int tid = blockIdx.x * blockDim.x + threadIdx.x;
    int stride = gridDim.x * blockDim.x;
    int lane = threadIdx.x & 63;
    int wave_base = ((tid >> 6) << 7) + lane;  // wave covers [w*128, w*128+128)
    float acc = 0.0f;

    int s = 0;
    for (; s + 2 * stride <= n4; s += 2 * stride) {
        int i0 = s + wave_base;
        int i1 = i0 + 64;
        float4 a0 = x[i0];
        float4 a1 = x[i1];
        float4 b0 = tg[i0];
        float4 b1 = tg[i1];
        acc += awl_quad(a0, b0);
        acc += awl_quad(a1, b1);
    }
    // generic tail (not hit for n4 % (2*stride) == 0)
    for (int i = s + tid; i < n4; i += stride)
        acc += awl_quad(x[i], tg[i]);

    // wave-64 reduce
    #pragma unroll
    for (int off = 32; off > 0; off >>= 1)
        acc += __shfl_down(acc, off, 64);
    __shared__ float ws[4];
    int wid = threadIdx.x >> 6;
    if (lane == 0) ws[wid] = acc;
    __syncthreads();
    if (threadIdx.x == 0)
        part[blockIdx.x] = (ws[0] + ws[1]) + (ws[2] + ws[3]);
}

__global__ __launch_bounds__(256) void awl_final(
    const float* __restrict__ part, int n, float* __restrict__ out)
{
    float acc = 0.0f;
    for (int i = threadIdx.x; i < n; i += 256) acc += part[i];
    #pragma unroll
    for (int off = 32; off > 0; off >>= 1)
        acc += __shfl_down(acc, off, 64);
    __shared__ float ws[4];
    int lane = threadIdx.x & 63;
    int wid  = threadIdx.x >> 6;
    if (lane == 0) ws[wid] = acc;
    __syncthreads();
    if (threadIdx.x == 0)
        out[0] = (ws[0] + ws[1]) + (ws[2] + ws[3]);
}

extern "C" void kernel_launch(void* const* d_in, const int* in_sizes, int n_in,
                              void* d_out, int out_size, void* d_ws, size_t ws_size,
                              hipStream_t stream) {
    const float* x  = (const float*)d_in[0];
    const float* tg = (const float*)d_in[1];
    float* out  = (float*)d_out;
    float* part = (float*)d_ws;

    long long n = (long long)in_sizes[0];   // 67,108,864 (divisible by 4)
    int n4 = (int)(n / 4);

    int nblk = 2048;                         // 8 blocks/CU -> 32 waves/CU
    int cap = (int)(ws_size / sizeof(float));
    if (cap > 0 && nblk > cap) nblk = cap;
    if (nblk < 1) nblk = 1;

    awl_partial<<<nblk, 256, 0, stream>>>((const float4*)x, (const float4*)tg, part, n4);
    awl_final<<<1, 256, 0, stream>>>(part, nblk, out);
}